// Round 4
// baseline (326.161 us; speedup 1.0000x reference)
//
#include <hip/hip_runtime.h>
#include <math.h>

#define BB 8
#define SS 4096
#define HH 1024
#define ROWS (BB * HH)   // 8192
#define KTOP 8
#define NS 32            // s-chunks; pairs ws = ROWS*NS*8*8B = 16.8 MB (proven fits)
#define SC (SS / NS)     // 128 s per thread (one chunk)
#define TS 8             // tile s-extent
#define NT (SC / TS)     // 16 tiles per chunk

// Sorted-descending top-8 insert; strict > keeps earlier (lower s) on ties,
// matching lax.top_k's lowest-index tie-break. Keys are t*exp(g) >= 0
// (same ordering as log(t)+g since exp is monotone); slots init to -1.
#define INSERT8(TS_, TV_, SCV, VALV) do {                                 \
    if ((SCV) > TS_[7]) {                                                 \
      TS_[7] = (SCV); TV_[7] = (VALV);                                    \
      _Pragma("unroll")                                                   \
      for (int _i = 7; _i > 0; --_i) {                                    \
        if (TS_[_i] > TS_[_i - 1]) {                                      \
          float _t = TS_[_i]; TS_[_i] = TS_[_i - 1]; TS_[_i - 1] = _t;    \
          float _v = TV_[_i]; TV_[_i] = TV_[_i - 1]; TV_[_i - 1] = _v;    \
        }                                                                 \
      }                                                                   \
    }                                                                     \
  } while (0)

// Kernel 1: per-(row, s-chunk) top-8 of key = relu(h)*exp(g).
// Block = 256 rows (thread<->row, lane<->h), chunk = SC s. Hidden is staged
// through LDS in [TS s x 256 h] tiles loaded as float4 (16B/lane = 1KB
// contiguous per wave-instr -> HBM-friendly granules), double-buffered with
// ONE barrier per tile: iter t issues global loads for t+1, computes tile t
// from LDS, ds_writes t+1 into the other buffer, then syncs. Gumbel rides in
// registers (float4 per 4 s, L1 line reuse). No logf: one v_exp_f32 per elem.
// pairs layout: [r][c][j] float2 -> merge reads are contiguous per row.
__global__ __launch_bounds__(256) void topk_partial(
    const float* __restrict__ hidden, const float* __restrict__ gumbel,
    float2* __restrict__ pairs) {
  __shared__ float lh[2][TS * 256];   // 16 KB total

  const int tid = threadIdx.x;
  const int sc  = blockIdx.x;
  const int rb  = blockIdx.y;
  const int r   = rb * 256 + tid;
  const int b   = rb >> 2;            // 256 rows never straddle a b boundary
  const int h0  = (rb & 3) << 8;
  const int s0  = sc * SC;

  const float* __restrict__ hbase = hidden + (size_t)b * SS * HH + h0;
  const float4* __restrict__ gp =
      (const float4*)(gumbel + (size_t)r * SS + s0);

  // staging coords: flat f = p*256+tid -> si = p*4 + (tid>>6), hq = tid&63
  const int sil = tid >> 6;           // wave index = s-row within half-tile
  const int hq  = tid & 63;

  float ts[KTOP], tv[KTOP];
#pragma unroll
  for (int i = 0; i < KTOP; ++i) { ts[i] = -1.0f; tv[i] = 0.0f; }

  // prologue: stage tile 0, load gumbel for tile 0
  {
#pragma unroll
    for (int p = 0; p < 2; ++p) {
      const int si = p * 4 + sil;
      const float4 v = *(const float4*)&hbase[(size_t)(s0 + si) * HH + hq * 4];
      *(float4*)&lh[0][si * 256 + hq * 4] = v;
    }
  }
  float4 g0 = gp[0], g1 = gp[1];
  __syncthreads();

  for (int t = 0; t < NT; ++t) {
    const int cur = t & 1;
    float4 nh0, nh1, ng0, ng1;
    if (t + 1 < NT) {   // issue next tile's global loads early
      const int sb = s0 + (t + 1) * TS;
      nh0 = *(const float4*)&hbase[(size_t)(sb + sil) * HH + hq * 4];
      nh1 = *(const float4*)&hbase[(size_t)(sb + 4 + sil) * HH + hq * 4];
      ng0 = gp[2 * (t + 1)];
      ng1 = gp[2 * (t + 1) + 1];
    }
    const float g[8] = {g0.x, g0.y, g0.z, g0.w, g1.x, g1.y, g1.z, g1.w};
#pragma unroll
    for (int si = 0; si < TS; ++si) {
      const float tt  = fmaxf(lh[cur][si * 256 + tid], 0.0f);
      const float key = tt * __expf(g[si]);   // rank-equiv to log(t)+g; 0 if t==0
      INSERT8(ts, tv, key, tt);
    }
    if (t + 1 < NT) {
      *(float4*)&lh[cur ^ 1][(sil) * 256 + hq * 4]     = nh0;
      *(float4*)&lh[cur ^ 1][(4 + sil) * 256 + hq * 4] = nh1;
      g0 = ng0; g1 = ng1;
    }
    __syncthreads();
  }

  float2* __restrict__ op = pairs + ((size_t)r * NS + sc) * KTOP;
#pragma unroll
  for (int j = 0; j < KTOP; ++j) op[j] = make_float2(ts[j], tv[j]);
}

// Kernel 2: merge NS chunk top-8s per row -> pooled[r] = sum of top-8 values.
// 8 threads/row, each merges NS/8 contiguous chunks (512B contiguous reads),
// 3-level LDS tree (ascending group order preserves tie-break).
// grid ROWS/32 = 256 blocks; block 256.
__global__ __launch_bounds__(256) void topk_merge(
    const float2* __restrict__ pairs, float* __restrict__ pooled) {
  __shared__ float2 ls[256 * 9];    // [slot=rloc*8+q][j], padded
  const int tid  = threadIdx.x;
  const int rloc = tid >> 3;        // 0..31
  const int q    = tid & 7;         // chunk group
  const int r    = blockIdx.x * 32 + rloc;
  const int slot = rloc * 8 + q;

  float ts[KTOP], tv[KTOP];
#pragma unroll
  for (int i = 0; i < KTOP; ++i) { ts[i] = -INFINITY; tv[i] = 0.0f; }

  const int cpg = NS / 8;           // chunks per group
  const float4* __restrict__ p =
      (const float4*)(pairs + ((size_t)r * NS + q * cpg) * KTOP);
#pragma unroll
  for (int i = 0; i < cpg * KTOP / 2; ++i) {
    const float4 two = p[i];        // two (key,val) pairs
    INSERT8(ts, tv, two.x, two.y);
    INSERT8(ts, tv, two.z, two.w);
  }
#pragma unroll
  for (int j = 0; j < KTOP; ++j) ls[slot * 9 + j] = make_float2(ts[j], tv[j]);
  __syncthreads();
  if ((q & 1) == 0) {               // level 1: (0,1)(2,3)(4,5)(6,7)
#pragma unroll
    for (int j = 0; j < KTOP; ++j) {
      const float2 pp = ls[(slot + 1) * 9 + j];
      INSERT8(ts, tv, pp.x, pp.y);
    }
#pragma unroll
    for (int j = 0; j < KTOP; ++j) ls[slot * 9 + j] = make_float2(ts[j], tv[j]);
  }
  __syncthreads();
  if ((q & 3) == 0) {               // level 2: (0,2)(4,6)
#pragma unroll
    for (int j = 0; j < KTOP; ++j) {
      const float2 pp = ls[(slot + 2) * 9 + j];
      INSERT8(ts, tv, pp.x, pp.y);
    }
#pragma unroll
    for (int j = 0; j < KTOP; ++j) ls[slot * 9 + j] = make_float2(ts[j], tv[j]);
  }
  __syncthreads();
  if (q == 0) {                     // level 3: (0,4) -> final sum
#pragma unroll
    for (int j = 0; j < KTOP; ++j) {
      const float2 pp = ls[(slot + 4) * 9 + j];
      INSERT8(ts, tv, pp.x, pp.y);
    }
    float sum = 0.0f;
#pragma unroll
    for (int j = 0; j < KTOP; ++j) sum += tv[j];
    // all-zero rows: slots hold (0-key, 0-value) entries -> sum 0 = reference
    pooled[r] = sum;
  }
}

// Kernel 3: out[b][j] = tanh(sum_h pooled[b][h] * W[j][h] + bias[j]).
// grid 256 blocks x 4 waves; one wave per output column j. W read once via
// float4 (1KB per wave-instr); pooled staged to LDS; shuffle-reduce over lanes.
__global__ __launch_bounds__(256) void linear_tanh(
    const float* __restrict__ pooled, const float* __restrict__ W,
    const float* __restrict__ bias, float* __restrict__ out) {
  __shared__ float lp[ROWS];  // 32 KB: full pooled
  const int tid = threadIdx.x;
#pragma unroll
  for (int i = 0; i < ROWS / 4 / 256; ++i)
    ((float4*)lp)[i * 256 + tid] = ((const float4*)pooled)[i * 256 + tid];
  __syncthreads();

  const int wave = tid >> 6;
  const int lane = tid & 63;
  const int j = blockIdx.x * 4 + wave;

  float acc[BB];
#pragma unroll
  for (int bb = 0; bb < BB; ++bb) acc[bb] = 0.0f;
#pragma unroll
  for (int k0 = 0; k0 < HH; k0 += 256) {
    const float4 w4 = *(const float4*)&W[(size_t)j * HH + k0 + lane * 4];
#pragma unroll
    for (int bb = 0; bb < BB; ++bb) {
      const float4 p4 = *(const float4*)&lp[bb * HH + k0 + lane * 4];
      acc[bb] += w4.x * p4.x + w4.y * p4.y + w4.z * p4.z + w4.w * p4.w;
    }
  }
#pragma unroll
  for (int bb = 0; bb < BB; ++bb) {
    float a = acc[bb];
    for (int off = 32; off > 0; off >>= 1) a += __shfl_down(a, off, 64);
    if (lane == 0) out[(size_t)bb * HH + j] = tanhf(a + bias[j]);
  }
}

extern "C" void kernel_launch(void* const* d_in, const int* in_sizes, int n_in,
                              void* d_out, int out_size, void* d_ws, size_t ws_size,
                              hipStream_t stream) {
  const float* hidden = (const float*)d_in[0];
  const float* gumbel = (const float*)d_in[1];
  const float* W      = (const float*)d_in[2];
  const float* bias   = (const float*)d_in[3];
  float* out          = (float*)d_out;

  float2* pairs  = (float2*)d_ws;
  float*  pooled = (float*)((char*)d_ws
                   + (size_t)ROWS * NS * KTOP * sizeof(float2));

  topk_partial<<<dim3(NS, 32), dim3(256), 0, stream>>>(hidden, gumbel, pairs);
  topk_merge<<<dim3(ROWS / 32), dim3(256), 0, stream>>>(pairs, pooled);
  linear_tanh<<<dim3(HH / 4), dim3(256), 0, stream>>>(pooled, W, bias, out);
}